// Round 7
// baseline (150.707 us; speedup 1.0000x reference)
//
#include <hip/hip_runtime.h>

#define B_ 8
#define C_ 256
#define S_ 2048

typedef short s8v __attribute__((ext_vector_type(8)));
typedef short s4v __attribute__((ext_vector_type(4)));
typedef float f4v __attribute__((ext_vector_type(4)));

__device__ inline short f2b(float f){            // fp32 -> bf16 RNE
  unsigned u = __builtin_bit_cast(unsigned, f);
  unsigned r = (u + 0x7FFFu + ((u >> 16) & 1u)) >> 16;
  return (short)r;
}
__device__ inline float b2f(short s){
  unsigned u = ((unsigned)(unsigned short)s) << 16;
  return __builtin_bit_cast(float, u);
}

// K1: weight (R,C,M) fp32 -> wT (R,M,C) bf16
__global__ __launch_bounds__(256) void k_tw(const float* __restrict__ wgt, short* __restrict__ wT){
  int bid = blockIdx.x;
  int r  = bid >> 4;
  int ct = (bid >> 2) & 3;
  int mt = bid & 3;
  __shared__ float tile[64][65];
  int tid = threadIdx.x;
  const float* wb = wgt + r*(C_*256);
  #pragma unroll
  for (int it = 0; it < 4; ++it){
    int row = it*16 + (tid >> 4);
    int m4  = tid & 15;
    float4 v = *(const float4*)(wb + (ct*64 + row)*256 + mt*64 + m4*4);
    tile[row][m4*4+0] = v.x; tile[row][m4*4+1] = v.y;
    tile[row][m4*4+2] = v.z; tile[row][m4*4+3] = v.w;
  }
  __syncthreads();
  #pragma unroll
  for (int it = 0; it < 4; ++it){
    int mrow = it*16 + (tid >> 4);
    int c4   = tid & 15;
    s4v o;
    o[0] = f2b(tile[c4*4+0][mrow]); o[1] = f2b(tile[c4*4+1][mrow]);
    o[2] = f2b(tile[c4*4+2][mrow]); o[3] = f2b(tile[c4*4+3][mrow]);
    *(s4v*)(wT + r*65536 + (mt*64 + mrow)*256 + ct*64 + c4*4) = o;
  }
}

// Ablation template. V=0 stage+sort; V=1 +B-loads; V=2 +full R6 e-loop; V=4 pipelined
// e-loop; V=5 FULL (R6 exact, writes outputs). Non-5 variants write nothing to d_out;
// phases kept live via asm keep-alives.
template<int V>
__global__ __launch_bounds__(256,2) void k_abl(const float* __restrict__ x,
    const short* __restrict__ wT, const float* __restrict__ bias,
    const int* __restrict__ idx, const int* __restrict__ rate,
    float* __restrict__ outx, float* __restrict__ outm, float* __restrict__ idx_out)
{
  int bid = blockIdx.x;
  int quarter = (bid >> 3) & 3;
  int tile = (bid & 7) | ((bid >> 5) << 3);
  int b  = tile >> 5;
  int s0 = (tile & 31) << 6;
  int m0b = quarter << 6;

  __shared__ short A[64*256];
  __shared__ float biasS[8*64];
  __shared__ int eOrd[64];
  __shared__ int eSlot[64];
  __shared__ int rateO64[64];
  __shared__ int eRange[4];
  __shared__ int lcount[8], lbase[8], rateE[8];

  int tid  = threadIdx.x;
  int lane = tid & 63, wv = tid >> 6;
  int l15  = lane & 15, lq = lane >> 4;

  if (tid < 8){ lcount[tid] = 0; rateE[tid] = rate[tid]; }
  {
    int e = tid >> 5, j = (tid & 31)*2;
    float2 bv2 = *(const float2*)(bias + e*256 + m0b + j);
    biasS[e*64 + j] = bv2.x; biasS[e*64 + j + 1] = bv2.y;
  }
  __syncthreads();

  int myE = 0, myRank = 0;
  if (tid < 64){
    myE = idx[b*S_ + s0 + tid] & 7;
    myRank = atomicAdd(&lcount[myE], 1);
  }

  // ---- stage A: 4x4 register transpose, b64 LDS writes ----
  char* AB = (char*)A;
  {
    const float* xb = x + b*(C_*S_) + s0;
    int sq  = tid & 15;
    int cq0 = tid >> 4;
    #pragma unroll
    for (int it = 0; it < 4; ++it){
      int cq = it*16 + cq0;
      float4 v0 = *(const float4*)(xb + (cq*4+0)*S_ + sq*4);
      float4 v1 = *(const float4*)(xb + (cq*4+1)*S_ + sq*4);
      float4 v2 = *(const float4*)(xb + (cq*4+2)*S_ + sq*4);
      float4 v3 = *(const float4*)(xb + (cq*4+3)*S_ + sq*4);
      int sw = ((sq & 7) << 4);
      s4v o;
      o[0]=f2b(v0.x); o[1]=f2b(v1.x); o[2]=f2b(v2.x); o[3]=f2b(v3.x);
      *(s4v*)(AB + (((sq*4+0)*512 + cq*8) ^ sw)) = o;
      o[0]=f2b(v0.y); o[1]=f2b(v1.y); o[2]=f2b(v2.y); o[3]=f2b(v3.y);
      *(s4v*)(AB + (((sq*4+1)*512 + cq*8) ^ sw)) = o;
      o[0]=f2b(v0.z); o[1]=f2b(v1.z); o[2]=f2b(v2.z); o[3]=f2b(v3.z);
      *(s4v*)(AB + (((sq*4+2)*512 + cq*8) ^ sw)) = o;
      o[0]=f2b(v0.w); o[1]=f2b(v1.w); o[2]=f2b(v2.w); o[3]=f2b(v3.w);
      *(s4v*)(AB + (((sq*4+3)*512 + cq*8) ^ sw)) = o;
    }
  }
  __syncthreads();
  if (tid == 0){
    int a0 = 0;
    #pragma unroll
    for (int e = 0; e < 8; ++e){ lbase[e] = a0; a0 += lcount[e]; }
  }
  __syncthreads();
  if (tid < 64){
    int q = lbase[myE] + myRank;
    eOrd[q]  = tid;
    eSlot[q] = myE;
    rateO64[tid] = rateE[myE] >> 5;
    if constexpr (V == 5){
      if (quarter == 0) idx_out[b*S_ + s0 + tid] = (float)myE;
    }
  }
  __syncthreads();
  if (tid < 4) eRange[tid] = eSlot[tid*16] | (eSlot[tid*16 + 15] << 8);
  __syncthreads();

  int mw = m0b + wv*16;

  int epk[4], rpk[4], prow[4], psw[4];
  #pragma unroll
  for (int mi = 0; mi < 4; ++mi){
    int qb = mi*16 + lq*4;
    int e0 = eSlot[qb+0], e1 = eSlot[qb+1], e2 = eSlot[qb+2], e3 = eSlot[qb+3];
    epk[mi] = e0 | (e1 << 8) | (e2 << 16) | (e3 << 24);
    rpk[mi] = (rateE[e0] >> 5) | ((rateE[e1] >> 5) << 8)
            | ((rateE[e2] >> 5) << 16) | ((rateE[e3] >> 5) << 24);
    prow[mi] = eOrd[mi*16 + l15];
    psw[mi]  = ((prow[mi] >> 2) & 7) << 4;
  }

  if constexpr (V == 0){
    short z = ((short*)A)[(tid*37) & 16383];     // dynamic read keeps stage writes live
    asm volatile("" :: "v"((int)z), "v"(epk[0]), "v"(rpk[0]), "v"(prow[0]), "v"(psw[0]));
    return;
  }

  if constexpr (V == 1){
    // B-load rounds only, same gating/order as FULL; values kept live, no MFMA.
    for (int e = 0; e < 8; ++e){
      if (lcount[e] == 0 || rateE[e] <= mw) continue;
      const short* bp = wT + e*65536 + (mw + l15)*256 + lq*8;
      s8v bv[8];
      #pragma unroll
      for (int k = 0; k < 8; ++k){
        bv[k] = *(const s8v*)(bp + k*32);
        asm volatile("" :: "v"(bv[k]));
      }
    }
    short z = ((short*)A)[(tid*37) & 16383];
    asm volatile("" :: "v"((int)z), "v"(epk[0]), "v"(prow[0]));
    return;
  }

  f4v acc[4];
  #pragma unroll
  for (int mi = 0; mi < 4; ++mi) acc[mi] = (f4v){0.f,0.f,0.f,0.f};

  if constexpr (V == 2 || V == 5){
    // R6's exact e-loop: K split halves, inline ds_read -> MFMA chain
    for (int e = 0; e < 8; ++e){
      if (lcount[e] == 0 || rateE[e] <= mw) continue;
      const short* bp = wT + e*65536 + (mw + l15)*256;
      float bs = biasS[e*64 + wv*16 + l15];
      f4v t[4];
      #pragma unroll
      for (int mi = 0; mi < 4; ++mi) t[mi] = (f4v){0.f,0.f,0.f,0.f};
      #pragma unroll
      for (int kq = 0; kq < 2; ++kq){
        s8v bv[4];
        #pragma unroll
        for (int kk = 0; kk < 4; ++kk)
          bv[kk] = *(const s8v*)(bp + (kq*4+kk)*32 + lq*8);
        #pragma unroll
        for (int mi = 0; mi < 4; ++mi){
          int rg = eRange[mi];
          if (e < (rg & 255) || e > (rg >> 8)) continue;
          #pragma unroll
          for (int kk = 0; kk < 4; ++kk){
            s8v a = *(const s8v*)(AB + ((prow[mi]*512 + (kq*4+kk)*64 + lq*16) ^ psw[mi]));
            t[mi] = __builtin_amdgcn_mfma_f32_16x16x32_bf16(a, bv[kk], t[mi], 0, 0, 0);
          }
        }
      }
      #pragma unroll
      for (int mi = 0; mi < 4; ++mi){
        #pragma unroll
        for (int r = 0; r < 4; ++r){
          bool hit = (((epk[mi] >> (r*8)) & 255) == e);
          acc[mi][r] = hit ? (t[mi][r] + bs) : acc[mi][r];
        }
      }
    }
  }

  if constexpr (V == 4){
    // pipelined: double-buffered B prefetch (compile-time ping-pong), batched a8 reads
    bool act[8];
    #pragma unroll
    for (int e = 0; e < 8; ++e) act[e] = (lcount[e] != 0) && (rateE[e] > mw);
    s8v bvA[8], bvB[8];
    auto loadB = [&](int e, s8v (&dst)[8]){
      const short* bp = wT + e*65536 + (mw + l15)*256 + lq*8;
      #pragma unroll
      for (int k = 0; k < 8; ++k) dst[k] = *(const s8v*)(bp + k*32);
    };
    auto comp = [&](int e, s8v (&bv)[8]){
      float bs = biasS[e*64 + wv*16 + l15];
      #pragma unroll
      for (int mi = 0; mi < 4; ++mi){
        int rg = eRange[mi];
        if (e < (rg & 255) || e > (rg >> 8)) continue;
        s8v a8[8];
        #pragma unroll
        for (int kk = 0; kk < 8; ++kk)
          a8[kk] = *(const s8v*)(AB + ((prow[mi]*512 + kk*64 + lq*16) ^ psw[mi]));
        f4v t = (f4v){0.f,0.f,0.f,0.f};
        #pragma unroll
        for (int kk = 0; kk < 8; ++kk)
          t = __builtin_amdgcn_mfma_f32_16x16x32_bf16(a8[kk], bv[kk], t, 0, 0, 0);
        #pragma unroll
        for (int r = 0; r < 4; ++r){
          bool hit = (((epk[mi] >> (r*8)) & 255) == e);
          acc[mi][r] = hit ? (t[r] + bs) : acc[mi][r];
        }
      }
    };
    if (act[0]) loadB(0, bvA);
    #pragma unroll
    for (int e = 0; e < 8; ++e){
      if (e + 1 < 8 && act[e+1]){
        if (e & 1) loadB(e+1, bvA); else loadB(e+1, bvB);
      }
      if (act[e]){
        if (e & 1) comp(e, bvB); else comp(e, bvA);
      }
    }
  }

  if constexpr (V == 2 || V == 4){
    asm volatile("" :: "v"(acc[0]), "v"(acc[1]), "v"(acc[2]), "v"(acc[3]));
    return;
  }

  if constexpr (V == 5){
    // ---- epilogue: residual + rate mask, reuse A as fp32 out-stage ----
    float vals[16];
    int mk = mw >> 5;
    #pragma unroll
    for (int mi = 0; mi < 4; ++mi){
      #pragma unroll
      for (int r = 0; r < 4; ++r){
        int q = mi*16 + lq*4 + r;
        int srow = eOrd[q];
        float xres = b2f(*(const short*)(AB + ((srow*512 + (mw + l15)*2) ^ (((srow >> 2) & 7) << 4))));
        int rt32 = (rpk[mi] >> (r*8)) & 255;
        vals[mi*4 + r] = (mk < rt32) ? (acc[mi][r] + xres) : 0.0f;
      }
    }
    __syncthreads();
    float* AF = (float*)A;
    #pragma unroll
    for (int mi = 0; mi < 4; ++mi){
      #pragma unroll
      for (int r = 0; r < 4; ++r){
        int q = mi*16 + lq*4 + r;
        AF[(wv*16 + l15)*65 + eOrd[q]] = vals[mi*4 + r];
      }
    }
    __syncthreads();
    {
      int sv = (tid & 15)*4;
      float* ob = outx + b*(C_*S_) + s0;
      float* om = outm + b*(C_*S_) + s0;
      #pragma unroll
      for (int it = 0; it < 4; ++it){
        int ml = it*16 + (tid >> 4);
        int mg = m0b + ml;
        int mks = mg >> 5;
        float4 v = *(const float4*)&AF[ml*65 + sv];
        float4 omv;
        omv.x = (mks < rateO64[sv+0]) ? 1.0f : 0.0f;
        omv.y = (mks < rateO64[sv+1]) ? 1.0f : 0.0f;
        omv.z = (mks < rateO64[sv+2]) ? 1.0f : 0.0f;
        omv.w = (mks < rateO64[sv+3]) ? 1.0f : 0.0f;
        v.x = omv.x != 0.0f ? v.x : 0.0f;
        v.y = omv.y != 0.0f ? v.y : 0.0f;
        v.z = omv.z != 0.0f ? v.z : 0.0f;
        v.w = omv.w != 0.0f ? v.w : 0.0f;
        *(float4*)(ob + mg*S_ + sv) = v;
        *(float4*)(om + mg*S_ + sv) = omv;
      }
    }
  }
}

extern "C" void kernel_launch(void* const* d_in, const int* in_sizes, int n_in,
                              void* d_out, int out_size, void* d_ws, size_t ws_size,
                              hipStream_t stream){
  const float* x    = (const float*)d_in[0];
  const int*   idx  = (const int*)d_in[1];
  const float* wgt  = (const float*)d_in[2];
  const float* bias = (const float*)d_in[3];
  const int*   rate = (const int*)d_in[4];

  short* wT = (short*)d_ws;

  float* outx    = (float*)d_out;
  float* outm    = outx + (B_*C_*S_);
  float* idx_out = outx + 2*(B_*C_*S_);

  k_tw<<<128, 256, 0, stream>>>(wgt, wT);
  // Instrumented ablation round: dur_us is intentionally the SUM of variants.
  k_abl<0><<<1024, 256, 0, stream>>>(x, wT, bias, idx, rate, outx, outm, idx_out);
  k_abl<1><<<1024, 256, 0, stream>>>(x, wT, bias, idx, rate, outx, outm, idx_out);
  k_abl<2><<<1024, 256, 0, stream>>>(x, wT, bias, idx, rate, outx, outm, idx_out);
  k_abl<4><<<1024, 256, 0, stream>>>(x, wT, bias, idx, rate, outx, outm, idx_out);
  k_abl<5><<<1024, 256, 0, stream>>>(x, wT, bias, idx, rate, outx, outm, idx_out);
}

// Round 9
// 40.153 us; speedup vs baseline: 3.7533x; 3.7533x over previous
//
#include <hip/hip_runtime.h>

#define B_ 8
#define C_ 256
#define S_ 2048
#define T_ (B_*S_)      // 16384 tokens

typedef short s8v __attribute__((ext_vector_type(8)));
typedef short s4v __attribute__((ext_vector_type(4)));
typedef float f4v __attribute__((ext_vector_type(4)));

__device__ inline short f2b(float f){            // fp32 -> bf16 RNE
  unsigned u = __builtin_bit_cast(unsigned, f);
  unsigned r = (u + 0x7FFFu + ((u >> 16) & 1u)) >> 16;
  return (short)r;
}
__device__ inline float b2f(short s){
  unsigned u = ((unsigned)(unsigned short)s) << 16;
  return __builtin_bit_cast(float, u);
}

// K1: fused prep, 1216 blocks.
//  blocks    0-1023: x (B,C,S) fp32 -> xT token-major bf16 (proven R3 transpose)
//  blocks 1024-1151: weight (R,C,M) fp32 -> wT2 bf16 tiled [r][kc 8][n 256][k32] (linear,
//                    no swizzle -- consumed global->VGPR, coalesced 1KB per (ni,kc))
//  blocks 1152-1215: bucket tokens by expert (LDS-aggregated atomics) + idx passthrough
__global__ __launch_bounds__(256) void k_pre(const float* __restrict__ x, short* __restrict__ xT,
                                             const float* __restrict__ wgt, short* __restrict__ wT2,
                                             const int* __restrict__ idx, int* __restrict__ counts,
                                             int* __restrict__ bucket, float* __restrict__ idx_out){
  __shared__ float tile[64][65];
  __shared__ int lcount[8];
  __shared__ int lbase[8];
  int tid = threadIdx.x;
  int bid = blockIdx.x;

  if (bid < 1024){
    int b  = bid >> 7;
    int ct = (bid >> 5) & 3;
    int st = bid & 31;
    const float* xb = x + b*(C_*S_);
    #pragma unroll
    for (int it = 0; it < 4; ++it){
      int row = it*16 + (tid >> 4);       // c-local
      int s4  = tid & 15;
      float4 v = *(const float4*)(xb + (ct*64 + row)*S_ + st*64 + s4*4);
      tile[row][s4*4+0] = v.x; tile[row][s4*4+1] = v.y;
      tile[row][s4*4+2] = v.z; tile[row][s4*4+3] = v.w;
    }
    __syncthreads();
    #pragma unroll
    for (int it = 0; it < 4; ++it){
      int srow = it*16 + (tid >> 4);      // s-local
      int c4   = tid & 15;
      s4v o;
      o[0] = f2b(tile[c4*4+0][srow]); o[1] = f2b(tile[c4*4+1][srow]);
      o[2] = f2b(tile[c4*4+2][srow]); o[3] = f2b(tile[c4*4+3][srow]);
      *(s4v*)(xT + (b*S_ + st*64 + srow)*C_ + ct*64 + c4*4) = o;
    }
  } else if (bid < 1152){
    int wb_ = bid - 1024;
    int r  = wb_ >> 4;
    int ct = (wb_ >> 2) & 3;   // c-tile (K dim)
    int mt = wb_ & 3;          // n-tile
    const float* wsrc = wgt + r*(C_*256);
    #pragma unroll
    for (int it = 0; it < 4; ++it){
      int row = it*16 + (tid >> 4);       // c-local
      int m4  = tid & 15;
      float4 v = *(const float4*)(wsrc + (ct*64 + row)*256 + mt*64 + m4*4);
      tile[row][m4*4+0] = v.x; tile[row][m4*4+1] = v.y;
      tile[row][m4*4+2] = v.z; tile[row][m4*4+3] = v.w;
    }
    __syncthreads();
    char* wdst = (char*)wT2 + r*131072;
    #pragma unroll
    for (int it = 0; it < 2; ++it){
      int q  = it*256 + tid;              // 512 chunks: 64 n x 8 c-chunks
      int ml = q >> 3;                    // n-local
      int ck = q & 7;                     // 8 consecutive c
      int mg = mt*64 + ml;
      int cg = ct*64 + ck*8;
      int kcb = cg >> 5, klocal = cg & 31;
      s8v o;
      #pragma unroll
      for (int j = 0; j < 8; ++j) o[j] = f2b(tile[ck*8 + j][ml]);
      *(s8v*)(wdst + kcb*16384 + mg*64 + klocal*2) = o;   // linear [kc][n][k32]
    }
  } else {
    int t = (bid - 1152)*256 + tid;
    if (tid < 8) lcount[tid] = 0;
    __syncthreads();
    int ei = idx[t];
    int e  = ei & 7;
    int lp = atomicAdd(&lcount[e], 1);
    __syncthreads();
    if (tid < 8){
      int c = lcount[tid];
      lbase[tid] = c ? atomicAdd(counts + tid, c) : 0;
    }
    __syncthreads();
    bucket[e*T_ + lbase[e] + lp] = t;
    idx_out[t] = (float)ei;
  }
}

// K2: grouped GEMM. Block = (expert, 32-token tile slot), grid 512 = 8 x 64.
// A (16KB, XOR (row&7)<<4) staged reg->LDS; B-fragments DIRECT global->VGPR from wT2
// (L2-resident, coalesced) -> NO K-loop barriers, fully unrolled kc. Epilogue fuses
// bias+residual+rate-mask, restages bf16 via OS (XOR (row&3)<<5), bursts to yT.
__global__ __launch_bounds__(256,2) void k_gemm(const short* __restrict__ xT, const short* __restrict__ wT2,
                                                const float* __restrict__ bias, const int* __restrict__ counts,
                                                const int* __restrict__ bucket, const int* __restrict__ rate,
                                                short* __restrict__ yT){
  int e    = blockIdx.x >> 6;
  int slot = blockIdx.x & 63;
  int cnt  = counts[e];

  __shared__ short A [32*256];     // 16KB
  __shared__ short OS[32*256];     // 16KB out-stage
  __shared__ float biasS[256];
  __shared__ int   toks[32];

  int tid  = threadIdx.x;
  int lane = tid & 63, wv = tid >> 6;
  int l15  = lane & 15, lq = lane >> 4;

  biasS[tid] = bias[e*256 + tid];
  int rate_e = rate[e];
  const char* wTe = (const char*)wT2 + e*131072;
  char* AB  = (char*)A;
  char* OSB = (char*)OS;

  for (int tile = slot; tile*32 < cnt; tile += 64){
    int rowsV = cnt - tile*32; if (rowsV > 32) rowsV = 32;
    __syncthreads();                    // protect toks/A from previous iteration readers
    if (tid < 32)
      toks[tid] = bucket[e*T_ + tile*32 + (tid < rowsV ? tid : rowsV - 1)];
    __syncthreads();

    // ---- stage A: 8 threads per token row, 64B each, reg->LDS swizzled ----
    {
      int row = tid >> 3, ck = tid & 7;
      const char* src = (const char*)xT + toks[row]*512 + ck*64;
      s8v v0 = *(const s8v*)(src);
      s8v v1 = *(const s8v*)(src + 16);
      s8v v2 = *(const s8v*)(src + 32);
      s8v v3 = *(const s8v*)(src + 48);
      int base = row*512, swz = (row & 7) << 4;
      *(s8v*)(AB + base + ((ck*64 +  0) ^ swz)) = v0;
      *(s8v*)(AB + base + ((ck*64 + 16) ^ swz)) = v1;
      *(s8v*)(AB + base + ((ck*64 + 32) ^ swz)) = v2;
      *(s8v*)(AB + base + ((ck*64 + 48) ^ swz)) = v3;
    }
    __syncthreads();

    f4v acc[2][4];
    #pragma unroll
    for (int mi = 0; mi < 2; ++mi)
      #pragma unroll
      for (int ni = 0; ni < 4; ++ni) acc[mi][ni] = (f4v){0.f,0.f,0.f,0.f};

    int aswz = (l15 & 7) << 4;
    #pragma unroll
    for (int kc = 0; kc < 8; ++kc){
      s8v a0 = *(const s8v*)(AB + l15*512        + ((kc*64 + lq*16) ^ aswz));
      s8v a1 = *(const s8v*)(AB + (16 + l15)*512 + ((kc*64 + lq*16) ^ aswz));
      #pragma unroll
      for (int ni = 0; ni < 4; ++ni){
        int n = wv*64 + ni*16 + l15;
        s8v bv = *(const s8v*)(wTe + kc*16384 + n*64 + lq*16);
        acc[0][ni] = __builtin_amdgcn_mfma_f32_16x16x32_bf16(a0, bv, acc[0][ni], 0, 0, 0);
        acc[1][ni] = __builtin_amdgcn_mfma_f32_16x16x32_bf16(a1, bv, acc[1][ni], 0, 0, 0);
      }
    }

    // ---- epilogue: bias + residual + rate-mask -> OS (bf16) ----
    #pragma unroll
    for (int mi = 0; mi < 2; ++mi){
      #pragma unroll
      for (int ni = 0; ni < 4; ++ni){
        int col = wv*64 + ni*16 + l15;
        float bs = biasS[col];
        bool keep = col < rate_e;
        #pragma unroll
        for (int r = 0; r < 4; ++r){
          int row = mi*16 + lq*4 + r;
          float xres = b2f(*(const short*)(AB + row*512 + ((col*2) ^ ((row & 7) << 4))));
          float val  = keep ? (acc[mi][ni][r] + xres + bs) : 0.0f;
          *(short*)(OSB + row*512 + ((col*2) ^ ((row & 3) << 5))) = f2b(val);
        }
      }
    }
    __syncthreads();
    // ---- burst store: content at (row, off) belongs to col*2 = off ^ ((row&3)<<5) ----
    #pragma unroll
    for (int r2 = 0; r2 < 4; ++r2){
      int q = r2*4096 + tid*16;
      int row = q >> 9, off = q & 511;
      if (row < rowsV)
        *(s8v*)((char*)yT + toks[row]*512 + (off ^ ((row & 3) << 5))) = *(const s8v*)(OSB + q);
    }
  }
}

// K3: yT token-major bf16 (pre-masked) -> outx (B,C,S) fp32 + outm; coalesced along s.
__global__ __launch_bounds__(256) void k_final(const short* __restrict__ yT, const int* __restrict__ idx,
                                               const int* __restrict__ rate_choice,
                                               float* __restrict__ outx, float* __restrict__ outm){
  int bid = blockIdx.x;
  int b  = bid >> 7;
  int ct = (bid >> 5) & 3;
  int st = bid & 31;
  __shared__ float tile[64][65];
  __shared__ int rateS[64];
  int tid = threadIdx.x;
  if (tid < 64) rateS[tid] = rate_choice[idx[b*S_ + st*64 + tid] & 7] >> 5;
  #pragma unroll
  for (int it = 0; it < 4; ++it){
    int srow = it*16 + (tid >> 4);
    int c4   = tid & 15;
    s4v v = *(const s4v*)(yT + (b*S_ + st*64 + srow)*C_ + ct*64 + c4*4);
    tile[c4*4+0][srow] = b2f(v[0]); tile[c4*4+1][srow] = b2f(v[1]);
    tile[c4*4+2][srow] = b2f(v[2]); tile[c4*4+3][srow] = b2f(v[3]);
  }
  __syncthreads();
  #pragma unroll
  for (int it = 0; it < 16; ++it){
    int cl = it*4 + (tid >> 6);
    int sl = tid & 63;
    int cg = ct*64 + cl;
    float v = tile[cl][sl];
    bool keep = (cg >> 5) < rateS[sl];
    int off = b*(C_*S_) + cg*S_ + st*64 + sl;
    outx[off] = v;                      // yT pre-masked in k_gemm
    outm[off] = keep ? 1.0f : 0.0f;
  }
}

extern "C" void kernel_launch(void* const* d_in, const int* in_sizes, int n_in,
                              void* d_out, int out_size, void* d_ws, size_t ws_size,
                              hipStream_t stream){
  const float* x    = (const float*)d_in[0];
  const int*   idx  = (const int*)d_in[1];
  const float* wgt  = (const float*)d_in[2];
  const float* bias = (const float*)d_in[3];
  const int*   rate = (const int*)d_in[4];

  char* ws = (char*)d_ws;
  short* xT     = (short*)ws;                  // 8 MB token-major bf16
  short* wT2    = (short*)(ws + 8388608);      // 1 MB tiled weights [r][kc][n][k32]
  int*   bucket = (int*)  (ws + 9437184);      // 512 KB
  int*   counts = (int*)  (ws + 9961472);      // 32 B
  short* yT     = (short*)(ws + 10485760);     // 8 MB token-major bf16 (masked y)

  float* outx    = (float*)d_out;
  float* outm    = outx + (B_*C_*S_);
  float* idx_out = outx + 2*(B_*C_*S_);

  hipMemsetAsync(counts, 0, 32, stream);
  k_pre  <<<1216, 256, 0, stream>>>(x, xT, wgt, wT2, idx, counts, bucket, idx_out);
  k_gemm <<<512,  256, 0, stream>>>(xT, wT2, bias, counts, bucket, rate, yT);
  k_final<<<1024, 256, 0, stream>>>(yT, idx, rate, outx, outm);
}